// Round 4
// baseline (183.782 us; speedup 1.0000x reference)
//
#include <hip/hip_runtime.h>
#include <hip/hip_bf16.h>
#include <cstdint>
#include <cstddef>

#define B_DIM 256
#define T_DIM 256
#define EMB   384
#define HEAD  64

typedef __attribute__((ext_vector_type(8))) short bf16x8;
typedef __attribute__((ext_vector_type(4))) float f32x4;
typedef __attribute__((ext_vector_type(4))) unsigned int u32x4;

__device__ __forceinline__ unsigned short f2bf(float f) {
    union { float f; unsigned int u; } v; v.f = f;
    unsigned int r = v.u + 0x7fffu + ((v.u >> 16) & 1u);  // RNE
    return (unsigned short)(r >> 16);
}

__device__ __forceinline__ unsigned int pkbf(float a, float b) {
#if __has_builtin(__builtin_amdgcn_cvt_pk_bf16_f32)
    typedef __attribute__((ext_vector_type(2))) __bf16 bf16x2_t;
    bf16x2_t r = __builtin_amdgcn_cvt_pk_bf16_f32(a, b);
    return *(unsigned int*)&r;
#else
    return (unsigned)f2bf(a) | ((unsigned)f2bf(b) << 16);
#endif
}

// Workspace layout (bytes): Wb at 0 (147,456 B); q_swz @1MB, k_swz @16MB,
// vT_swz @32MB (each 256 batches * 32,768 B = 8.39 MB). ws >= 402 MB.
#define WS_Q_OFF  (1u  << 20)
#define WS_K_OFF  (16u << 20)
#define WS_V_OFF  (32u << 20)

// ---------------------------------------------------------------------------
// Kernel 0: W prep — Wq|Wk|Wv fp32 [384][64] -> Wb bf16, chunk-permuted for
// global_load_lds staging (chunk cs of col r holds source chunk cs^(r&7)).
// Unchanged from v1 (proven).
// ---------------------------------------------------------------------------
__global__ void wprep_kernel(const float* __restrict__ Wq, const float* __restrict__ Wk,
                             const float* __restrict__ Wv, unsigned short* __restrict__ Wb) {
    int g = blockIdx.x * blockDim.x + threadIdx.x;
    if (g >= 9216) return;                 // 6 k-steps * 1536 chunks
    int kkstep = g / 1536, rem = g - kkstep * 1536;
    int r = rem >> 3, cs = rem & 7, c = cs ^ (r & 7);
    const float* W = (r < 64) ? Wq : (r < 128) ? Wk : Wv;
    int h = r & 63;
    unsigned short tmp[8];
#pragma unroll
    for (int e = 0; e < 8; ++e) {
        int k = kkstep * 64 + c * 8 + e;
        tmp[e] = f2bf(W[k * HEAD + h]);
    }
    *(u32x4*)(Wb + (size_t)g * 8) = *(u32x4*)tmp;
}

// ---------------------------------------------------------------------------
// Kernel A: QKV GEMM. v5 structural split: the fused kernel was latency-bound
// (all pipes <15% busy) because one 8-wave block owned each CU with serial
// barrier-locked phases. Now: 512 blocks x 4 waves (batch b=bid>>1, token
// half p=bid&1 -> M=128 rows, N=192, K=384), LDS = Xs(2x128x64 swizzled,
// 32K) + Ws(2x12288, 48K) = 80 KiB -> 2 blocks/CU; one block's x-stream
// overlaps the other's MFMA. Wave tile = v1's proven 64x96 acc[4][6]
// (10 ds_read_b128 / 24 MFMA). Outputs to workspace bf16:
//   q_swz/k_swz[b][256][64]: 16B-chunk c of token row stored at c^(tok&7)
//   vT_swz[b][64][256]: tok-chunk t (16B=8 tok) stored at low3(t)^=(ch&7)
// so kernel B can global_load_lds them LINEARLY and read conflict-free.
// ---------------------------------------------------------------------------
__global__ __launch_bounds__(256) void qkv_kernel(const float* __restrict__ x,
                                                  const unsigned short* __restrict__ Wb,
                                                  unsigned short* __restrict__ qg,
                                                  unsigned short* __restrict__ kg,
                                                  unsigned short* __restrict__ vg) {
    __shared__ union SM {
        struct { unsigned short Xs[2][128][64]; unsigned short Ws[2][12288]; } p1;  // 81,920 B
        struct { unsigned short qb[128][64]; unsigned short kb[128][64];
                 unsigned short vTb[64][128]; } p2;                                 // 49,152 B
    } sm;

    const int tid = threadIdx.x;
    const int w = tid >> 6, lane = tid & 63, qd = lane >> 4, l15 = lane & 15;
    const int mh = w >> 1, nh = w & 1;            // 2x2 wave grid: 64 x 96 tile
    const int b = blockIdx.x >> 1, p = blockIdx.x & 1;
    const float* xb = x + ((size_t)b * T_DIM + p * 128) * EMB;
    const int xrow = tid >> 4, fc = tid & 15;     // x-stage: 16 rows x 16 float4

#define WGLDS(KSTEP, BUF) do { \
    _Pragma("unroll") \
    for (int s = 0; s < 6; ++s) { \
        int idx = s * 256 + w * 64; \
        const unsigned short* gp = Wb + (size_t)((KSTEP) * 1536 + idx + lane) * 8; \
        unsigned short* lp = &sm.p1.Ws[BUF][idx * 8]; \
        __builtin_amdgcn_global_load_lds( \
            (const __attribute__((address_space(1))) unsigned int*)gp, \
            (__attribute__((address_space(3))) unsigned int*)lp, 16, 0, 0); \
    } \
} while (0)

    // x loads for k-step KK: 8 row-groups, float4 each (16 lanes x 16 B = 256 B/row)
#define XLOAD(KK) do { \
    _Pragma("unroll") \
    for (int s = 0; s < 8; ++s) \
        xr[s] = *(const float4*)(xb + (size_t)(xrow + 16 * s) * EMB + (KK) * 64 + 4 * fc); \
} while (0)

    // convert + XOR-swizzled Xs write (image: chunk c of row stored at c^(row&7))
#define XWRITE(BUF) do { \
    _Pragma("unroll") \
    for (int s = 0; s < 8; ++s) { \
        int row_ = xrow + 16 * s; \
        *(uint2*)((char*)&sm.p1.Xs[BUF][0][0] + row_ * 128 + \
                  ((((fc >> 1) ^ (row_ & 7)) << 4) | ((fc & 1) << 3))) = \
            make_uint2(pkbf(xr[s].x, xr[s].y), pkbf(xr[s].z, xr[s].w)); \
    } \
} while (0)

    float4 xr[8];
    WGLDS(0, 0);
    XLOAD(0);
    XWRITE(0);

    f32x4 acc[4][6];
#pragma unroll
    for (int mt = 0; mt < 4; ++mt)
#pragma unroll
        for (int nt = 0; nt < 6; ++nt) acc[mt][nt] = (f32x4){0.f, 0.f, 0.f, 0.f};

#pragma unroll
    for (int kk = 0; kk < 6; ++kk) {
        __syncthreads();   // drains glds (vmcnt) + Xs writes (lgkm)
        if (kk < 5) {
            WGLDS(kk + 1, (kk + 1) & 1);
            XLOAD(kk + 1);
        }
#pragma unroll
        for (int kb = 0; kb < 2; ++kb) {
            bf16x8 a[4], bb[6];
#pragma unroll
            for (int mt = 0; mt < 4; ++mt) {
                int rl = 64 * mh + 16 * mt + l15;
                a[mt] = *(const bf16x8*)((const char*)&sm.p1.Xs[kk & 1][0][0] +
                                         rl * 128 + ((((kb << 2) + qd) ^ (rl & 7)) << 4));
            }
#pragma unroll
            for (int nt = 0; nt < 6; ++nt) {
                int n = 96 * nh + 16 * nt + l15;
                bb[nt] = *(const bf16x8*)&sm.p1.Ws[kk & 1][n * 64 + (((4 * kb + qd) ^ (n & 7)) << 3)];
            }
#pragma unroll
            for (int mt = 0; mt < 4; ++mt)
#pragma unroll
                for (int nt = 0; nt < 6; ++nt)
                    acc[mt][nt] = __builtin_amdgcn_mfma_f32_16x16x32_bf16(a[mt], bb[nt], acc[mt][nt], 0, 0, 0);
        }
        if (kk < 5) XWRITE((kk + 1) & 1);
    }
    __syncthreads();       // all GEMM LDS reads done; repurpose union as bounce

    // scatter acc -> bounce (C/D layout: col=l15(ch), row=4*qd+reg(tok)).
    // q/k land PRE-SWIZZLED (chunk c at c^(tok&7)); vT plain [64][128].
#pragma unroll
    for (int nt = 0; nt < 6; ++nt) {
        int n = 96 * nh + 16 * nt + l15;
        int arr = n >> 6, hh = n & 63;         // wave-uniform per nt
        if (arr == 2) {
#pragma unroll
            for (int mt = 0; mt < 4; ++mt) {
                int tok0 = 64 * mh + 16 * mt + 4 * qd;
                *(uint2*)&sm.p2.vTb[hh][tok0] = make_uint2(
                    pkbf(acc[mt][nt][0], acc[mt][nt][1]),
                    pkbf(acc[mt][nt][2], acc[mt][nt][3]));
            }
        } else {
            char* base = (arr == 0) ? (char*)&sm.p2.qb[0][0] : (char*)&sm.p2.kb[0][0];
#pragma unroll
            for (int mt = 0; mt < 4; ++mt)
#pragma unroll
                for (int reg = 0; reg < 4; ++reg) {
                    int tok = 64 * mh + 16 * mt + 4 * qd + reg;
                    *(unsigned short*)(base + tok * 128 +
                        ((((hh >> 3) ^ (tok & 7)) << 4) | ((hh & 7) << 1))) = f2bf(acc[mt][nt][reg]);
                }
        }
    }
    __syncthreads();       // bounce ready

    // coalesced stores: q/k images are already in target (swizzled) layout.
    {
        int row = tid >> 1, cb = (tid & 1) * 4;
        size_t gq = (size_t)b * 32768 + (p * 128 + row) * 128;
#pragma unroll
        for (int i = 0; i < 4; ++i) {
            *(u32x4*)((char*)qg + gq + (cb + i) * 16) =
                *(const u32x4*)((const char*)&sm.p2.qb[0][0] + row * 128 + (cb + i) * 16);
            *(u32x4*)((char*)kg + gq + (cb + i) * 16) =
                *(const u32x4*)((const char*)&sm.p2.kb[0][0] + row * 128 + (cb + i) * 16);
        }
        // vT: row ch (512 B/row of 256 tok); apply swizzle on the global address
        int ch = tid >> 2, cg = (tid & 3) * 4;
#pragma unroll
        for (int i = 0; i < 4; ++i) {
            int cl = cg + i;   // local 16B tok-chunk 0..15
            u32x4 v = *(const u32x4*)((const char*)&sm.p2.vTb[0][0] + ch * 256 + cl * 16);
            *(u32x4*)((char*)vg + (size_t)b * 32768 + ch * 512 + p * 256 +
                      ((cl & 8) << 4) + (((cl & 7) ^ (ch & 7)) << 4)) = v;
        }
    }
}

// ---------------------------------------------------------------------------
// Kernel B: attention. 512 blocks x 4 waves (batch b=bid>>1, parity p=bid&1),
// 2 blocks/CU (LDS 74,752 B). Row-tiles {2w+p, 14-2w+p}: every block has
// 64 (p=0) or 72 (p=1) coltile-units and every wave 5 PV chunks — balanced.
// K/V staged via 16 linear global_load_lds (swizzle pre-applied by kernel A);
// Q frags read straight from global into registers. No barriers after
// staging -> waves run free; cross-block phase diversity hides latency.
// ---------------------------------------------------------------------------
__global__ __launch_bounds__(256) void attn_kernel(const unsigned short* __restrict__ qg,
                                                   const unsigned short* __restrict__ kg,
                                                   const unsigned short* __restrict__ vg,
                                                   float* __restrict__ out) {
    __shared__ struct {
        unsigned short ks[256][64];    // 32,768 B (chunk c at c^(tok&7))
        unsigned short vT[64][256];    // 32,768 B (tok-chunk low3 ^= ch&7)
        unsigned short Ps[4][16][72];  //  9,216 B
    } sm;

    const int tid = threadIdx.x;
    const int w = tid >> 6, lane = tid & 63, qd = lane >> 4, l15 = lane & 15;
    const int b = blockIdx.x >> 1, p = blockIdx.x & 1;

    // stage K and vT (linear; images pre-swizzled by kernel A)
#pragma unroll
    for (int s = 0; s < 8; ++s) {
        int idx = s * 256 + w * 64;
        __builtin_amdgcn_global_load_lds(
            (const __attribute__((address_space(1))) unsigned int*)(kg + (size_t)b * 16384 + (idx + lane) * 8),
            (__attribute__((address_space(3))) unsigned int*)(&sm.ks[0][0] + idx * 8), 16, 0, 0);
    }
#pragma unroll
    for (int s = 0; s < 8; ++s) {
        int idx = s * 256 + w * 64;
        __builtin_amdgcn_global_load_lds(
            (const __attribute__((address_space(1))) unsigned int*)(vg + (size_t)b * 16384 + (idx + lane) * 8),
            (__attribute__((address_space(3))) unsigned int*)(&sm.vT[0][0] + idx * 8), 16, 0, 0);
    }

    const int tiles[2] = { 2 * w + p, 14 - 2 * w + p };

    // Q frags straight from global (pre-swizzled layout, L2/L3-hit)
    bf16x8 aq[2][2];
#pragma unroll
    for (int ti = 0; ti < 2; ++ti)
#pragma unroll
        for (int kbi = 0; kbi < 2; ++kbi) {
            int row = 16 * tiles[ti] + l15;
            aq[ti][kbi] = *(const bf16x8*)((const char*)qg + (size_t)b * 32768 + row * 128 +
                                           ((((kbi << 2) + qd) ^ (l15 & 7)) << 4));
        }

    __syncthreads();       // K/vT staged (drains vmcnt)

    f32x4 O[2][4];
    float l[2][4];
#pragma unroll
    for (int ti = 0; ti < 2; ++ti) {
#pragma unroll
        for (int dn = 0; dn < 4; ++dn) O[ti][dn] = (f32x4){0.f, 0.f, 0.f, 0.f};
#pragma unroll
        for (int reg = 0; reg < 4; ++reg) l[ti][reg] = 0.f;
    }

    const float cExp = 1.4426950408889634f / 19.595917942265423f; // log2(e)/sqrt(384)

#pragma unroll
    for (int ti = 0; ti < 2; ++ti) {
        const int t = tiles[ti];
        for (int jc = 0; jc <= (t >> 2); ++jc) {
            const int ntmax = min(3, t - 4 * jc);
            f32x4 S[4];
#pragma unroll
            for (int nt = 0; nt < 4; ++nt) {
                if (nt <= ntmax) {
                    int rk = 64 * jc + 16 * nt + l15;
                    bf16x8 b0 = *(const bf16x8*)((const char*)&sm.ks[0][0] + rk * 128 +
                                                 ((qd ^ (l15 & 7)) << 4));
                    bf16x8 b1 = *(const bf16x8*)((const char*)&sm.ks[0][0] + rk * 128 +
                                                 (((4 + qd) ^ (l15 & 7)) << 4));
                    f32x4 s = __builtin_amdgcn_mfma_f32_16x16x32_bf16(aq[ti][0], b0, (f32x4){0.f,0.f,0.f,0.f}, 0, 0, 0);
                    s = __builtin_amdgcn_mfma_f32_16x16x32_bf16(aq[ti][1], b1, s, 0, 0, 0);
                    S[nt] = s;
                }
            }
#pragma unroll
            for (int nt = 0; nt < 4; ++nt) {
#pragma unroll
                for (int reg = 0; reg < 4; ++reg) {
                    float pv = 0.0f;
                    if (nt <= ntmax) {
                        pv = exp2f(S[nt][reg] * cExp);
                        if (4 * jc + nt == t && (l15 > 4 * qd + reg)) pv = 0.0f;  // diagonal mask
                    }
                    l[ti][reg] += pv;
                    sm.Ps[w][4 * qd + reg][16 * nt + l15] = f2bf(pv);
                }
            }
            // C-layout -> A-layout via wave-private strip (no barrier needed)
            bf16x8 ap0 = *(const bf16x8*)&sm.Ps[w][l15][8 * qd];
            bf16x8 ap1 = *(const bf16x8*)&sm.Ps[w][l15][32 + 8 * qd];
#pragma unroll
            for (int dn = 0; dn < 4; ++dn) {
                int rv = 16 * dn + l15;
                bf16x8 bv0 = *(const bf16x8*)((const char*)&sm.vT[0][0] + rv * 512 +
                                              ((8 * jc + (qd ^ (l15 & 7))) << 4));
                bf16x8 bv1 = *(const bf16x8*)((const char*)&sm.vT[0][0] + rv * 512 +
                                              ((8 * jc + ((4 + qd) ^ (l15 & 7))) << 4));
                O[ti][dn] = __builtin_amdgcn_mfma_f32_16x16x32_bf16(ap0, bv0, O[ti][dn], 0, 0, 0);
                O[ti][dn] = __builtin_amdgcn_mfma_f32_16x16x32_bf16(ap1, bv1, O[ti][dn], 0, 0, 0);
            }
        }
    }

#pragma unroll
    for (int ti = 0; ti < 2; ++ti) {
#pragma unroll
        for (int reg = 0; reg < 4; ++reg) {
            float s = l[ti][reg];
            s += __shfl_xor(s, 1);
            s += __shfl_xor(s, 2);
            s += __shfl_xor(s, 4);
            s += __shfl_xor(s, 8);
            float inv = 1.0f / s;
            int row = 16 * tiles[ti] + 4 * qd + reg;
            float* dst = out + ((size_t)b * T_DIM + row) * HEAD;
#pragma unroll
            for (int dn = 0; dn < 4; ++dn)
                dst[16 * dn + l15] = O[ti][dn][reg] * inv;
        }
    }
}

// ---------------------------------------------------------------------------
extern "C" void kernel_launch(void* const* d_in, const int* in_sizes, int n_in,
                              void* d_out, int out_size, void* d_ws, size_t ws_size,
                              hipStream_t stream) {
    const float* x  = (const float*)d_in[0];
    const float* Wq = (const float*)d_in[1];
    const float* Wk = (const float*)d_in[2];
    const float* Wv = (const float*)d_in[3];
    float* out = (float*)d_out;

    unsigned short* Wb = (unsigned short*)d_ws;
    unsigned short* qg = (unsigned short*)((char*)d_ws + WS_Q_OFF);
    unsigned short* kg = (unsigned short*)((char*)d_ws + WS_K_OFF);
    unsigned short* vg = (unsigned short*)((char*)d_ws + WS_V_OFF);

    wprep_kernel<<<36, 256, 0, stream>>>(Wq, Wk, Wv, Wb);
    qkv_kernel<<<2 * B_DIM, 256, 0, stream>>>(x, Wb, qg, kg, vg);
    attn_kernel<<<2 * B_DIM, 256, 0, stream>>>(qg, kg, vg, out);
}

// Round 5
// 173.037 us; speedup vs baseline: 1.0621x; 1.0621x over previous
//
#include <hip/hip_runtime.h>
#include <hip/hip_bf16.h>
#include <cstdint>
#include <cstddef>

#define B_DIM 256
#define T_DIM 256
#define EMB   384
#define HEAD  64

typedef __attribute__((ext_vector_type(8))) short bf16x8;
typedef __attribute__((ext_vector_type(4))) float f32x4;
typedef __attribute__((ext_vector_type(4))) unsigned int u32x4;

__device__ __forceinline__ unsigned short f2bf(float f) {
    union { float f; unsigned int u; } v; v.f = f;
    unsigned int r = v.u + 0x7fffu + ((v.u >> 16) & 1u);  // RNE
    return (unsigned short)(r >> 16);
}

__device__ __forceinline__ unsigned int pkbf(float a, float b) {
#if __has_builtin(__builtin_amdgcn_cvt_pk_bf16_f32)
    typedef __attribute__((ext_vector_type(2))) __bf16 bf16x2_t;
    bf16x2_t r = __builtin_amdgcn_cvt_pk_bf16_f32(a, b);
    return *(unsigned int*)&r;
#else
    return (unsigned)f2bf(a) | ((unsigned)f2bf(b) << 16);
#endif
}

// ---------------------------------------------------------------------------
// Kernel 0: W prep — Wq|Wk|Wv fp32 [384][64] -> Wb bf16, chunk-permuted for
// global_load_lds staging. Chunk g = kkstep*1536 + r*8 + cs holds the 8
// k-values of source chunk c = cs ^ (r&7) of output-col r in k-step kkstep.
// Unchanged from v1 (proven).
// ---------------------------------------------------------------------------
__global__ void wprep_kernel(const float* __restrict__ Wq, const float* __restrict__ Wk,
                             const float* __restrict__ Wv, unsigned short* __restrict__ Wb) {
    int g = blockIdx.x * blockDim.x + threadIdx.x;
    if (g >= 9216) return;                 // 6 k-steps * 1536 chunks
    int kkstep = g / 1536, rem = g - kkstep * 1536;
    int r = rem >> 3, cs = rem & 7, c = cs ^ (r & 7);
    const float* W = (r < 64) ? Wq : (r < 128) ? Wk : Wv;
    int h = r & 63;
    unsigned short tmp[8];
#pragma unroll
    for (int e = 0; e < 8; ++e) {
        int k = kkstep * 64 + c * 8 + e;
        tmp[e] = f2bf(W[k * HEAD + h]);
    }
    *(u32x4*)(Wb + (size_t)g * 8) = *(u32x4*)tmp;
}

// ---------------------------------------------------------------------------
// Fused kernel v6: one block per batch, 1024 threads (16 waves), 1 block/CU.
//
// Diagnosis driving v6: every fused profile shows ALL pipes idle (v4:
// MfmaUtil 7.4%, VALUBusy 13.5%, HBM 14.6%) -> latency-bound. v1-v4 ran
// 8 waves/CU = 2 waves/SIMD, barrier-locked, so each k-step's dependent
// chain (barrier -> ds_read -> MFMA -> cvt -> ds_write -> barrier) exposes
// raw LDS/L2 latency. v5's kernel split added a grid-wide drain + workspace
// round-trip and regressed. v6 keeps v1's proven fused skeleton (same
// barrier count, same LDS images, same numerics) but runs 16 waves
// (4 waves/SIMD) to double latency hiding:
//   - GEMM: wave grid 4x4 (wm=w>>2 rows, wn=w&3 cols), 64x48/wave,
//     acc[4][3] = 48 VGPR so the 128-VGPR cap of 4 waves/SIMD holds.
//   - Staging: 1024 threads -> 4 float4/thread per x k-step (was 8),
//     Ws glds in 2 rounds (2nd round waves 0-7 only).
//   - Attention: ONE 16-row tile per wave; SIMD-balanced map (SIMD s gets
//     tiles {2s, 2s+1, 15-2s, 14-2s}: equal cost 34/SIMD) -> softmax and
//     O stay wave-private, no cross-wave reduction. Ps gets 16 strips.
// LDS: p1 122,880 B / p2 144,384 B -> 1 block/CU.
// ---------------------------------------------------------------------------
__global__ __launch_bounds__(1024, 1) void fused_kernel(const float* __restrict__ x,
                                                        const unsigned short* __restrict__ Wb,
                                                        float* __restrict__ out) {
    __shared__ union SM {
        struct { unsigned short Xs[2][256][72]; unsigned short Ws[2][12288]; } p1;   // 122,880 B
        struct { unsigned short qs[256][72]; unsigned short ks[256][72];
                 unsigned short vT[64][264]; unsigned short Ps[16][16][72]; } p2;    // 144,384 B
    } sm;

    const int tid = threadIdx.x;
    const int w = tid >> 6, lane = tid & 63, qd = lane >> 4, l15 = lane & 15;
    const int wm = w >> 2, wn = w & 3;            // 4x4 wave grid: 64 x 48 tile
    const int b = blockIdx.x;
    const float* xb = x + (size_t)b * T_DIM * EMB;
    const int xrow = tid >> 2, xj = tid & 3;      // x-stage: 256 rows x 4 float4

    // Ws glds: stage k-step KSTEP into Ws[BUF]; 1536 16B-chunks, 2 rounds
#define WGLDS(KSTEP, BUF) do { \
    _Pragma("unroll") \
    for (int s = 0; s < 2; ++s) { \
        int idx = s * 1024 + w * 64; \
        if (idx < 1536) { \
            const unsigned short* gp = Wb + (size_t)((KSTEP) * 1536 + idx + lane) * 8; \
            unsigned short* lp = &sm.p1.Ws[BUF][idx * 8]; \
            __builtin_amdgcn_global_load_lds( \
                (const __attribute__((address_space(1))) unsigned int*)gp, \
                (__attribute__((address_space(3))) unsigned int*)lp, 16, 0, 0); \
        } \
    } \
} while (0)

    // x loads for k-step KK: 4 float4 (this thread's quarter of one row)
#define XLOAD(KK) do { \
    _Pragma("unroll") \
    for (int i = 0; i < 4; ++i) \
        xr[i] = *(const float4*)(xb + (size_t)xrow * EMB + (KK) * 64 + (4 * xj + i) * 4); \
} while (0)

    // convert + Xs write (same image as v1: row-major [256][72], uint2 chunks)
#define XWRITE(BUF) do { \
    _Pragma("unroll") \
    for (int i = 0; i < 4; ++i) \
        *(uint2*)&sm.p1.Xs[BUF][xrow][4 * (4 * xj + i)] = \
            make_uint2(pkbf(xr[i].x, xr[i].y), pkbf(xr[i].z, xr[i].w)); \
} while (0)

    float4 xr[4];
    WGLDS(0, 0);
    XLOAD(0);
    XWRITE(0);

    f32x4 acc[4][3];
#pragma unroll
    for (int mt = 0; mt < 4; ++mt)
#pragma unroll
        for (int nt = 0; nt < 3; ++nt) acc[mt][nt] = (f32x4){0.f, 0.f, 0.f, 0.f};

    // ---- main K loop: one barrier per k-step (v1 skeleton) ----
#pragma unroll
    for (int kk = 0; kk < 6; ++kk) {
        __syncthreads();   // drains prev glds (vmcnt) + Xs writes (lgkm)
        if (kk < 5) {
            WGLDS(kk + 1, (kk + 1) & 1);
            XLOAD(kk + 1);
        }
#pragma unroll
        for (int kb = 0; kb < 2; ++kb) {
            bf16x8 a[4], bb[3];
#pragma unroll
            for (int mt = 0; mt < 4; ++mt)
                a[mt] = *(const bf16x8*)&sm.p1.Xs[kk & 1][64 * wm + 16 * mt + l15][32 * kb + 8 * qd];
#pragma unroll
            for (int nt = 0; nt < 3; ++nt) {
                int n = 48 * wn + 16 * nt + l15;
                bb[nt] = *(const bf16x8*)&sm.p1.Ws[kk & 1][n * 64 + (((4 * kb + qd) ^ (n & 7)) << 3)];
            }
#pragma unroll
            for (int mt = 0; mt < 4; ++mt)
#pragma unroll
                for (int nt = 0; nt < 3; ++nt)
                    acc[mt][nt] = __builtin_amdgcn_mfma_f32_16x16x32_bf16(a[mt], bb[nt], acc[mt][nt], 0, 0, 0);
        }
        if (kk < 5) XWRITE((kk + 1) & 1);
    }
    __syncthreads();       // all GEMM LDS reads done; safe to repurpose union

    // scatter acc -> qs / ks / vT  (C/D layout: col=l15(ch), row=4*qd+reg(tok))
#pragma unroll
    for (int nt = 0; nt < 3; ++nt) {
        int n = 48 * wn + 16 * nt + l15;
        int arr = n >> 6, hh = n & 63;         // wave-uniform per (wn,nt)
        if (arr == 2) {                        // vT: token-contiguous -> packed b64
#pragma unroll
            for (int mt = 0; mt < 4; ++mt) {
                int tok0 = 64 * wm + 16 * mt + 4 * qd;
                *(uint2*)&sm.p2.vT[hh][tok0] = make_uint2(
                    pkbf(acc[mt][nt][0], acc[mt][nt][1]),
                    pkbf(acc[mt][nt][2], acc[mt][nt][3]));
            }
        } else {
#pragma unroll
            for (int mt = 0; mt < 4; ++mt)
#pragma unroll
                for (int reg = 0; reg < 4; ++reg) {
                    int tok = 64 * wm + 16 * mt + 4 * qd + reg;
                    unsigned short val = f2bf(acc[mt][nt][reg]);
                    if (arr == 0) sm.p2.qs[tok][hh] = val;
                    else          sm.p2.ks[tok][hh] = val;
                }
        }
    }
    __syncthreads();       // q/k/vT ready

    // ---------------- attention, fully in LDS ----------------
    // SIMD-balanced tile map: wave w (SIMD s=w&3, slot=w>>2) ->
    // slot 0: 2s, slot 1: 2s+1, slot 2: 15-2s, slot 3: 14-2s.
    // Each SIMD's 4 tiles cost (t+1) summing to 34 -> no tail imbalance.
    const int slot = w >> 2, sid = w & 3;
    const int t = (slot < 2) ? (2 * sid + slot) : (15 - 2 * sid - (slot & 1));

    bf16x8 aq[2];
#pragma unroll
    for (int kbi = 0; kbi < 2; ++kbi)
        aq[kbi] = *(const bf16x8*)&sm.p2.qs[16 * t + l15][32 * kbi + 8 * qd];

    f32x4 O[4];
    float l[4];
#pragma unroll
    for (int dn = 0; dn < 4; ++dn) O[dn] = (f32x4){0.f, 0.f, 0.f, 0.f};
#pragma unroll
    for (int reg = 0; reg < 4; ++reg) l[reg] = 0.f;

    const float cExp = 1.4426950408889634f / 19.595917942265423f; // log2(e)/sqrt(384)

    for (int jc = 0; jc <= (t >> 2); ++jc) {
        const int ntmax = min(3, t - 4 * jc);
        f32x4 S[4];
#pragma unroll
        for (int nt = 0; nt < 4; ++nt) {
            if (nt <= ntmax) {
                bf16x8 b0 = *(const bf16x8*)&sm.p2.ks[64 * jc + 16 * nt + l15][8 * qd];
                bf16x8 b1 = *(const bf16x8*)&sm.p2.ks[64 * jc + 16 * nt + l15][32 + 8 * qd];
                f32x4 s = __builtin_amdgcn_mfma_f32_16x16x32_bf16(aq[0], b0, (f32x4){0.f,0.f,0.f,0.f}, 0, 0, 0);
                s = __builtin_amdgcn_mfma_f32_16x16x32_bf16(aq[1], b1, s, 0, 0, 0);
                S[nt] = s;
            }
        }
#pragma unroll
        for (int nt = 0; nt < 4; ++nt) {
#pragma unroll
            for (int reg = 0; reg < 4; ++reg) {
                float p = 0.0f;
                if (nt <= ntmax) {
                    p = exp2f(S[nt][reg] * cExp);
                    if (4 * jc + nt == t && (l15 > 4 * qd + reg)) p = 0.0f;  // diagonal mask
                }
                l[reg] += p;
                sm.p2.Ps[w][4 * qd + reg][16 * nt + l15] = f2bf(p);
            }
        }
        // C-layout -> A-layout via wave-private strip (no barrier needed)
        bf16x8 ap0 = *(const bf16x8*)&sm.p2.Ps[w][l15][8 * qd];
        bf16x8 ap1 = *(const bf16x8*)&sm.p2.Ps[w][l15][32 + 8 * qd];
#pragma unroll
        for (int dn = 0; dn < 4; ++dn) {
            bf16x8 bv0 = *(const bf16x8*)&sm.p2.vT[16 * dn + l15][64 * jc + 8 * qd];
            bf16x8 bv1 = *(const bf16x8*)&sm.p2.vT[16 * dn + l15][64 * jc + 32 + 8 * qd];
            O[dn] = __builtin_amdgcn_mfma_f32_16x16x32_bf16(ap0, bv0, O[dn], 0, 0, 0);
            O[dn] = __builtin_amdgcn_mfma_f32_16x16x32_bf16(ap1, bv1, O[dn], 0, 0, 0);
        }
    }

#pragma unroll
    for (int reg = 0; reg < 4; ++reg) {
        float s = l[reg];
        s += __shfl_xor(s, 1);
        s += __shfl_xor(s, 2);
        s += __shfl_xor(s, 4);
        s += __shfl_xor(s, 8);
        float inv = 1.0f / s;
        int row = 16 * t + 4 * qd + reg;
        float* dst = out + ((size_t)b * T_DIM + row) * HEAD;
#pragma unroll
        for (int dn = 0; dn < 4; ++dn)
            dst[16 * dn + l15] = O[dn][reg] * inv;
    }
}

// ---------------------------------------------------------------------------
extern "C" void kernel_launch(void* const* d_in, const int* in_sizes, int n_in,
                              void* d_out, int out_size, void* d_ws, size_t ws_size,
                              hipStream_t stream) {
    const float* x  = (const float*)d_in[0];
    const float* Wq = (const float*)d_in[1];
    const float* Wk = (const float*)d_in[2];
    const float* Wv = (const float*)d_in[3];
    float* out = (float*)d_out;

    unsigned short* Wb = (unsigned short*)d_ws;   // 9216*8 bf16 = 147 KB

    wprep_kernel<<<36, 256, 0, stream>>>(Wq, Wk, Wv, Wb);
    fused_kernel<<<B_DIM, 1024, 0, stream>>>(x, Wb, out);
}

// Round 6
// 172.446 us; speedup vs baseline: 1.0657x; 1.0034x over previous
//
#include <hip/hip_runtime.h>
#include <hip/hip_bf16.h>
#include <cstdint>
#include <cstddef>

#define B_DIM 256
#define T_DIM 256
#define EMB   384
#define HEAD  64

typedef __attribute__((ext_vector_type(8))) short bf16x8;
typedef __attribute__((ext_vector_type(4))) float f32x4;
typedef __attribute__((ext_vector_type(4))) unsigned int u32x4;

__device__ __forceinline__ unsigned short f2bf(float f) {
    union { float f; unsigned int u; } v; v.f = f;
    unsigned int r = v.u + 0x7fffu + ((v.u >> 16) & 1u);  // RNE
    return (unsigned short)(r >> 16);
}

__device__ __forceinline__ unsigned int pkbf(float a, float b) {
#if __has_builtin(__builtin_amdgcn_cvt_pk_bf16_f32)
    typedef __attribute__((ext_vector_type(2))) __bf16 bf16x2_t;
    bf16x2_t r = __builtin_amdgcn_cvt_pk_bf16_f32(a, b);
    return *(unsigned int*)&r;
#else
    return (unsigned)f2bf(a) | ((unsigned)f2bf(b) << 16);
#endif
}

// ---------------------------------------------------------------------------
// Kernel 0: W prep — Wq|Wk|Wv fp32 [384][64] -> Wb bf16, chunk-permuted for
// global_load_lds staging. Unchanged from v1 (proven).
// ---------------------------------------------------------------------------
__global__ void wprep_kernel(const float* __restrict__ Wq, const float* __restrict__ Wk,
                             const float* __restrict__ Wv, unsigned short* __restrict__ Wb) {
    int g = blockIdx.x * blockDim.x + threadIdx.x;
    if (g >= 9216) return;                 // 6 k-steps * 1536 chunks
    int kkstep = g / 1536, rem = g - kkstep * 1536;
    int r = rem >> 3, cs = rem & 7, c = cs ^ (r & 7);
    const float* W = (r < 64) ? Wq : (r < 128) ? Wk : Wv;
    int h = r & 63;
    unsigned short tmp[8];
#pragma unroll
    for (int e = 0; e < 8; ++e) {
        int k = kkstep * 64 + c * 8 + e;
        tmp[e] = f2bf(W[k * HEAD + h]);
    }
    *(u32x4*)(Wb + (size_t)g * 8) = *(u32x4*)tmp;
}

// ---------------------------------------------------------------------------
// Fused kernel v7: one block per batch, 1024 threads (16 waves), 1 block/CU.
//
// Diagnosis: all non-spilled variants (v1/v4/v6, wildly different staging)
// land at ~55 us with EVERY pipe <15% busy. Per-CU pipe work sums to
// ~35-40 us (MFMA 4.4 + VALU 7.9 + LDS ~9 + HBM-share ~16) but runs
// SERIALLY: within a wave each barrier-step is load -> convert -> write ->
// barrier -> ds_read -> MFMA, so HBM, VALU, LDS and MFMA take turns.
// v7 splits roles so pipes run CONCURRENTLY each step:
//   - waves 0-11 (consumers): pure GEMM. 4(M)x3(N) grid, 64x64/wave,
//     acc[4][4]=64 VGPR, 16 ds_read_b128 + 32 MFMA per k-step, never
//     touch global memory -> no vmcnt stalls between MFMAs.
//   - waves 12-15 (producers): per k-step load the next 64KB x slice
//     (16 coalesced float4/thread: 16 rows x 64B per instr group),
//     convert to bf16, write Xs[next]; plus all Ws glds for next step.
// Same one-barrier-per-step skeleton, same LDS images, same numerics as
// v6; producers write buffer (kk+1)&1 while consumers read kk&1.
// Attention phase: identical to v6 (16 waves, SIMD-balanced tile map).
// LDS: p1 122,880 B / p2 144,384 B -> 1 block/CU.
// ---------------------------------------------------------------------------
__global__ __launch_bounds__(1024, 1) void fused_kernel(const float* __restrict__ x,
                                                        const unsigned short* __restrict__ Wb,
                                                        float* __restrict__ out) {
    __shared__ union SM {
        struct { unsigned short Xs[2][256][72]; unsigned short Ws[2][12288]; } p1;   // 122,880 B
        struct { unsigned short qs[256][72]; unsigned short ks[256][72];
                 unsigned short vT[64][264]; unsigned short Ps[16][16][72]; } p2;    // 144,384 B
    } sm;

    const int tid = threadIdx.x;
    const int w = tid >> 6, lane = tid & 63, qd = lane >> 4, l15 = lane & 15;
    const int b = blockIdx.x;
    const float* xb = x + (size_t)b * T_DIM * EMB;

    const bool prod = (w >= 12);
    const int wm = w & 3, wn2 = w >> 2;        // consumer tile (valid for w<12)
    const int pw = w - 12;                     // producer wave id (valid w>=12)
    const int pt = tid & 255;                  // producer thread id 0..255
    const int prow4 = pt >> 2, pj = pt & 3;    // 64 rows/pass x 4 float4-quarters

    // producers: stage Ws k-step KSTEP into Ws[BUF] (6 rounds x 4 waves)
#define PWGLDS(KSTEP, BUF) do { \
    _Pragma("unroll") \
    for (int s = 0; s < 6; ++s) { \
        int idx = s * 256 + pw * 64; \
        const unsigned short* gp = Wb + (size_t)((KSTEP) * 1536 + idx + lane) * 8; \
        unsigned short* lp = &sm.p1.Ws[BUF][idx * 8]; \
        __builtin_amdgcn_global_load_lds( \
            (const __attribute__((address_space(1))) unsigned int*)gp, \
            (__attribute__((address_space(3))) unsigned int*)lp, 16, 0, 0); \
    } \
} while (0)

    // producers: load k-step KK's 64KB x slice (4 passes of 64 rows;
    // per instr: 16 rows x 4 lanes covering contiguous 64 B -> coalesced)
#define PXLOAD(KK) do { \
    _Pragma("unroll") \
    for (int s = 0; s < 4; ++s) \
        _Pragma("unroll") \
        for (int i = 0; i < 4; ++i) \
            pxr[s][i] = *(const float4*)(xb + (size_t)(64 * s + prow4) * EMB + (KK) * 64 + (4 * pj + i) * 4); \
} while (0)

    // producers: convert + write Xs[BUF] (v6 image: row-major [256][72])
#define PXWRITE(BUF) do { \
    _Pragma("unroll") \
    for (int s = 0; s < 4; ++s) \
        _Pragma("unroll") \
        for (int i = 0; i < 4; ++i) \
            *(uint2*)&sm.p1.Xs[BUF][64 * s + prow4][4 * (4 * pj + i)] = \
                make_uint2(pkbf(pxr[s][i].x, pxr[s][i].y), pkbf(pxr[s][i].z, pxr[s][i].w)); \
} while (0)

    float4 pxr[4][4];
    if (prod) {
        PWGLDS(0, 0);
        PXLOAD(0);
        PXWRITE(0);
    }

    f32x4 acc[4][4];
#pragma unroll
    for (int mt = 0; mt < 4; ++mt)
#pragma unroll
        for (int nt = 0; nt < 4; ++nt) acc[mt][nt] = (f32x4){0.f, 0.f, 0.f, 0.f};

    // ---- main K loop: one barrier per k-step; roles split by wave ----
#pragma unroll
    for (int kk = 0; kk < 6; ++kk) {
        __syncthreads();   // drains producer glds (vmcnt) + Xs writes (lgkm)
        if (prod) {
            if (kk < 5) {
                PWGLDS(kk + 1, (kk + 1) & 1);
                PXLOAD(kk + 1);
                PXWRITE((kk + 1) & 1);
            }
        } else {
#pragma unroll
            for (int kb = 0; kb < 2; ++kb) {
                bf16x8 a[4], bb[4];
#pragma unroll
                for (int mt = 0; mt < 4; ++mt)
                    a[mt] = *(const bf16x8*)&sm.p1.Xs[kk & 1][64 * wm + 16 * mt + l15][32 * kb + 8 * qd];
#pragma unroll
                for (int nt = 0; nt < 4; ++nt) {
                    int n = 64 * wn2 + 16 * nt + l15;
                    bb[nt] = *(const bf16x8*)&sm.p1.Ws[kk & 1][n * 64 + (((4 * kb + qd) ^ (n & 7)) << 3)];
                }
#pragma unroll
                for (int mt = 0; mt < 4; ++mt)
#pragma unroll
                    for (int nt = 0; nt < 4; ++nt)
                        acc[mt][nt] = __builtin_amdgcn_mfma_f32_16x16x32_bf16(a[mt], bb[nt], acc[mt][nt], 0, 0, 0);
            }
        }
    }
    __syncthreads();       // all GEMM LDS reads done; safe to repurpose union

    // scatter acc -> qs / ks / vT (consumers only; wn2 selects array directly)
    if (!prod) {
#pragma unroll
        for (int nt = 0; nt < 4; ++nt) {
            int hh = 16 * nt + l15;            // channel within array
            if (wn2 == 2) {                    // vT: token-contiguous -> packed b64
#pragma unroll
                for (int mt = 0; mt < 4; ++mt) {
                    int tok0 = 64 * wm + 16 * mt + 4 * qd;
                    *(uint2*)&sm.p2.vT[hh][tok0] = make_uint2(
                        pkbf(acc[mt][nt][0], acc[mt][nt][1]),
                        pkbf(acc[mt][nt][2], acc[mt][nt][3]));
                }
            } else {
#pragma unroll
                for (int mt = 0; mt < 4; ++mt)
#pragma unroll
                    for (int reg = 0; reg < 4; ++reg) {
                        int tok = 64 * wm + 16 * mt + 4 * qd + reg;
                        unsigned short val = f2bf(acc[mt][nt][reg]);
                        if (wn2 == 0) sm.p2.qs[tok][hh] = val;
                        else          sm.p2.ks[tok][hh] = val;
                    }
            }
        }
    }
    __syncthreads();       // q/k/vT ready

    // ---------------- attention, fully in LDS (v6, verified) ----------------
    // SIMD-balanced tile map: wave w (SIMD s=w&3, slot=w>>2) ->
    // slot 0: 2s, slot 1: 2s+1, slot 2: 15-2s, slot 3: 14-2s.
    const int slot = w >> 2, sid = w & 3;
    const int t = (slot < 2) ? (2 * sid + slot) : (15 - 2 * sid - (slot & 1));

    bf16x8 aq[2];
#pragma unroll
    for (int kbi = 0; kbi < 2; ++kbi)
        aq[kbi] = *(const bf16x8*)&sm.p2.qs[16 * t + l15][32 * kbi + 8 * qd];

    f32x4 O[4];
    float l[4];
#pragma unroll
    for (int dn = 0; dn < 4; ++dn) O[dn] = (f32x4){0.f, 0.f, 0.f, 0.f};
#pragma unroll
    for (int reg = 0; reg < 4; ++reg) l[reg] = 0.f;

    const float cExp = 1.4426950408889634f / 19.595917942265423f; // log2(e)/sqrt(384)

    for (int jc = 0; jc <= (t >> 2); ++jc) {
        const int ntmax = min(3, t - 4 * jc);
        f32x4 S[4];
#pragma unroll
        for (int nt = 0; nt < 4; ++nt) {
            if (nt <= ntmax) {
                bf16x8 b0 = *(const bf16x8*)&sm.p2.ks[64 * jc + 16 * nt + l15][8 * qd];
                bf16x8 b1 = *(const bf16x8*)&sm.p2.ks[64 * jc + 16 * nt + l15][32 + 8 * qd];
                f32x4 s = __builtin_amdgcn_mfma_f32_16x16x32_bf16(aq[0], b0, (f32x4){0.f,0.f,0.f,0.f}, 0, 0, 0);
                s = __builtin_amdgcn_mfma_f32_16x16x32_bf16(aq[1], b1, s, 0, 0, 0);
                S[nt] = s;
            }
        }
#pragma unroll
        for (int nt = 0; nt < 4; ++nt) {
#pragma unroll
            for (int reg = 0; reg < 4; ++reg) {
                float p = 0.0f;
                if (nt <= ntmax) {
                    p = exp2f(S[nt][reg] * cExp);
                    if (4 * jc + nt == t && (l15 > 4 * qd + reg)) p = 0.0f;  // diagonal mask
                }
                l[reg] += p;
                sm.p2.Ps[w][4 * qd + reg][16 * nt + l15] = f2bf(p);
            }
        }
        // C-layout -> A-layout via wave-private strip (no barrier needed)
        bf16x8 ap0 = *(const bf16x8*)&sm.p2.Ps[w][l15][8 * qd];
        bf16x8 ap1 = *(const bf16x8*)&sm.p2.Ps[w][l15][32 + 8 * qd];
#pragma unroll
        for (int dn = 0; dn < 4; ++dn) {
            bf16x8 bv0 = *(const bf16x8*)&sm.p2.vT[16 * dn + l15][64 * jc + 8 * qd];
            bf16x8 bv1 = *(const bf16x8*)&sm.p2.vT[16 * dn + l15][64 * jc + 32 + 8 * qd];
            O[dn] = __builtin_amdgcn_mfma_f32_16x16x32_bf16(ap0, bv0, O[dn], 0, 0, 0);
            O[dn] = __builtin_amdgcn_mfma_f32_16x16x32_bf16(ap1, bv1, O[dn], 0, 0, 0);
        }
    }

#pragma unroll
    for (int reg = 0; reg < 4; ++reg) {
        float s = l[reg];
        s += __shfl_xor(s, 1);
        s += __shfl_xor(s, 2);
        s += __shfl_xor(s, 4);
        s += __shfl_xor(s, 8);
        float inv = 1.0f / s;
        int row = 16 * t + 4 * qd + reg;
        float* dst = out + ((size_t)b * T_DIM + row) * HEAD;
#pragma unroll
        for (int dn = 0; dn < 4; ++dn)
            dst[16 * dn + l15] = O[dn][reg] * inv;
    }
}

// ---------------------------------------------------------------------------
extern "C" void kernel_launch(void* const* d_in, const int* in_sizes, int n_in,
                              void* d_out, int out_size, void* d_ws, size_t ws_size,
                              hipStream_t stream) {
    const float* x  = (const float*)d_in[0];
    const float* Wq = (const float*)d_in[1];
    const float* Wk = (const float*)d_in[2];
    const float* Wv = (const float*)d_in[3];
    float* out = (float*)d_out;

    unsigned short* Wb = (unsigned short*)d_ws;   // 9216*8 bf16 = 147 KB

    wprep_kernel<<<36, 256, 0, stream>>>(Wq, Wk, Wv, Wb);
    fused_kernel<<<B_DIM, 1024, 0, stream>>>(x, Wb, out);
}